// Round 6
// baseline (449.549 us; speedup 1.0000x reference)
//
#include <hip/hip_runtime.h>

typedef __attribute__((ext_vector_type(8))) short short8;
typedef __attribute__((ext_vector_type(4))) float f32x4;
union frag_u { short8 v; unsigned short u[8]; };

#define AS1 212   // LSTM ping-pong stride (106 dw; col*106 mod 32 distinct for 16 cols -> conflict-free)
#define AS2 328   // tail stride (164 dw -> 2-way, free per m136)

__device__ __forceinline__ float bf2f(unsigned short b) {
  unsigned int u = ((unsigned int)b) << 16;
  float f; __builtin_memcpy(&f, &u, 4); return f;
}
__device__ __forceinline__ unsigned short f2bf(float f) {
  unsigned int u; __builtin_memcpy(&u, &f, 4);
  return (unsigned short)((u + 0x7FFFu + ((u >> 16) & 1u)) >> 16);
}
__device__ __forceinline__ unsigned short hi_of(float f) { return f2bf(f); }
__device__ __forceinline__ unsigned short lo_of(float f) {
  unsigned short h = f2bf(f); return f2bf(f - bf2f(h));
}
__device__ __forceinline__ float sigm(float x) {
  return __builtin_amdgcn_rcpf(1.f + __expf(-x));
}
__device__ __forceinline__ float tanh_(float x) {
  return 1.f - 2.f * __builtin_amdgcn_rcpf(1.f + __expf(2.f * x));
}

// sA(16 x K bf16, stride AS) @ W(K x N) -> sG[n][m] (stride 20)
// A-frag: lane holds A[m=lane&15][k=kc*32+quad*8+j]; B-frag: W[k][n=tile*16+(lane&15)]
// C/D: row m = quad*4+reg, col n = lane&15   [bench-verified R2/R5]
template <int AS, typename GetB, typename GetW>
__device__ __forceinline__ void mfma_layer(const unsigned short* sA, float* sG,
    int wave, int col, int quad, int kc_n, int ntiles, int N, GetB getb, GetW getw)
{
  for (int tile = wave; tile < ntiles; tile += 4) {
    int n = tile * 16 + col;
    float b = (n < N) ? getb(n) : 0.f;
    f32x4 acc = {b, b, b, b};
    for (int kc = 0; kc < kc_n; ++kc) {
      short8 a = *(const short8*)&sA[col * AS + kc * 32 + quad * 8];
      frag_u w;
      #pragma unroll
      for (int j = 0; j < 8; ++j) {
        int k = kc * 32 + quad * 8 + j;
        w.u[j] = (n < N) ? getw(k, n) : (unsigned short)0;
      }
      acc = __builtin_amdgcn_mfma_f32_16x16x32_bf16(a, w.v, acc, 0, 0, 0);
    }
    *(f32x4*)&sG[n * 20 + quad * 4] = acc;
  }
}

// relu(sG) -> sA: hi at [0,N), lo at [loOff,loOff+N), zero to Kpad  [bench-verified R5]
template <int AS>
__device__ __forceinline__ void relu_fill_lo(const float* sG, unsigned short* sA,
                                             int tid, int N, int loOff, int Kpad) {
  for (int idx = tid; idx < 16 * Kpad; idx += 256) {
    int m = idx & 15, n = idx >> 4;
    unsigned short v = 0;
    if (n < N)                            v = f2bf(fmaxf(sG[n * 20 + m], 0.f));
    else if (n >= loOff && n < loOff + N) v = lo_of(fmaxf(sG[(n - loOff) * 20 + m], 0.f));
    sA[m * AS + n] = v;
  }
}

__global__ __launch_bounds__(256) void value_net_kernel(
    const float* __restrict__ state,
    const float* __restrict__ wih, const float* __restrict__ whh,
    const float* __restrict__ bih, const float* __restrict__ bhh,
    const float* __restrict__ w1, const float* __restrict__ b1,
    const float* __restrict__ w2, const float* __restrict__ b2,
    const float* __restrict__ w3, const float* __restrict__ b3,
    const float* __restrict__ w4, const float* __restrict__ b4,
    float* __restrict__ out)
{
  // LSTM A cols (K=192): [x_hi 0..6 | x_lo 7..13 | x_hi 14..20 | h_hi 21..70 |
  //                       h_lo 71..120 | h_hi 121..170 | zero ..191]
  // paired W rows: [wih_hi | wih_hi | wih_lo | whh_hi | whh_hi | whh_lo]  (tri-product)
  __shared__ __align__(16) unsigned short sPP[2 * 16 * AS1];  // 13 568 B ping-pong
  __shared__ __align__(16) float sG[160 * 20];                // 12 800 B
  unsigned short* sA0 = sPP;
  unsigned short* sA1 = sPP + 16 * AS1;
  unsigned short* tA  = sPP;            // tail A (16*328 = 5248 ush <= 6784) aliases dead ping-pong

  const int tid  = threadIdx.x;
  const int wave = tid >> 6;
  const int lane = tid & 63;
  const int col  = lane & 15;
  const int quad = lane >> 4;
  const int r0   = blockIdx.x * 16;

  // ---- persistent gate-separated LSTM weight fragments (hi/lo from f32) ----
  const int  uu  = wave * 16 + col;
  const bool uok = uu < 50;
  frag_u wf[4][6];
  float  wb[4];
  #pragma unroll
  for (int g = 0; g < 4; ++g) {
    int c = g * 50 + uu;
    #pragma unroll
    for (int kc = 0; kc < 6; ++kc) {
      #pragma unroll
      for (int j = 0; j < 8; ++j) {
        int k = kc * 32 + quad * 8 + j;
        unsigned short w = 0;
        if (uok) {
          if (k < 7)        w = hi_of(wih[k * 200 + c]);
          else if (k < 14)  w = hi_of(wih[(k - 7) * 200 + c]);
          else if (k < 21)  w = lo_of(wih[(k - 14) * 200 + c]);
          else if (k < 71)  w = hi_of(whh[(k - 21) * 200 + c]);
          else if (k < 121) w = hi_of(whh[(k - 71) * 200 + c]);
          else if (k < 171) w = lo_of(whh[(k - 121) * 200 + c]);
        }
        wf[g][kc].u[j] = w;
      }
    }
    wb[g] = uok ? (bih[c] + bhh[c]) : 0.f;
  }

  // ---- x ownership: isx threads own (row xm, dim xd); prefetch x_0, x_1 ----
  const int  xm = tid / 7, xd = tid - (tid / 7) * 7;
  const bool isx = tid < 112;
  float xv0 = 0.f, xcur = 0.f;
  if (isx) {
    const float* xs = state + (size_t)(r0 + xm) * 832 + 6 + xd;
    xv0  = xs[0];
    xcur = xs[13];
  }

  // ---- zero both ping-pong buffers (h0 = 0 and all padding) ----
  {
    unsigned int* a32 = (unsigned int*)sPP;
    #pragma unroll
    for (int i = 0; i < 14; ++i) {
      int idx = tid + i * 256;
      if (idx < (2 * 16 * AS1) / 2) a32[idx] = 0;
    }
  }
  __syncthreads();
  if (isx) {   // x_0 into buf0
    unsigned short h = f2bf(xv0), l = f2bf(xv0 - bf2f(h));
    sA0[xm * AS1 + xd] = h; sA0[xm * AS1 + 7 + xd] = l; sA0[xm * AS1 + 14 + xd] = h;
  }
  __syncthreads();

  float cst[4] = {0.f, 0.f, 0.f, 0.f};

  // ---- LSTM: 64 steps, ONE barrier per step (ping-pong; write-set disjoint from read-set) ----
  for (int t = 0; t < 64; ++t) {
    const unsigned short* Ar = (t & 1) ? sA1 : sA0;
    unsigned short*       Aw = (t & 1) ? sA0 : sA1;

    // issue x_{t+2} load at top of body: a full step (~1k cyc) to cover L2/L3 latency,
    // so the compiler's pre-barrier vmcnt(0) drain is already satisfied.
    float xnext = 0.f;
    if (isx && t < 62)
      xnext = state[(size_t)(r0 + xm) * 832 + (t + 2) * 13 + 6 + xd];

    short8 a[6];
    #pragma unroll
    for (int kc = 0; kc < 6; ++kc)
      a[kc] = *(const short8*)&Ar[col * AS1 + kc * 32 + quad * 8];

    f32x4 G[4];
    #pragma unroll
    for (int g = 0; g < 4; ++g) {
      float b = wb[g];
      f32x4 acc = {b, b, b, b};
      #pragma unroll
      for (int kc = 0; kc < 6; ++kc)
        acc = __builtin_amdgcn_mfma_f32_16x16x32_bf16(a[kc], wf[g][kc].v, acc, 0, 0, 0);
      G[g] = acc;
    }

    // activation in registers: lane holds all 4 gates of unit uu, rows m = quad*4 + r
    #pragma unroll
    for (int r = 0; r < 4; ++r) {
      float si = sigm(G[0][r]);
      float sf = sigm(G[1][r]);
      float tg = tanh_(G[2][r]);
      float so = sigm(G[3][r]);
      float cc = sf * cst[r] + si * tg;
      cst[r] = cc;
      float h = so * tanh_(cc);
      if (uok) {
        int m = quad * 4 + r;
        if (t < 63) {
          unsigned short hb = f2bf(h);
          unsigned short hl = f2bf(h - bf2f(hb));
          Aw[m * AS1 + 21 + uu]  = hb;
          Aw[m * AS1 + 71 + uu]  = hl;
          Aw[m * AS1 + 121 + uu] = hb;
        } else {
          sG[uu * 20 + m] = h;     // final h, full f32, sG is dead during the loop
        }
      }
    }
    if (isx && t < 63) {   // x_{t+1} into Aw (cols 0..20, disjoint from h cols)
      unsigned short h = f2bf(xcur), l = f2bf(xcur - bf2f(h));
      Aw[xm * AS1 + xd] = h; Aw[xm * AS1 + 7 + xd] = l; Aw[xm * AS1 + 14 + xd] = h;
      xcur = xnext;
    }
    __syncthreads();
  }

  // ---- tail prep over the (dead) ping-pong region ----
  // joint cols (stride AS2): [self_hi 0..5 | h_hi 6..55 | self_lo 56..61 | h_lo 62..111 | 0 ..127]
  {
    unsigned int* a32 = (unsigned int*)tA;
    #pragma unroll
    for (int i = 0; i < 11; ++i) {
      int idx = tid + i * 256;
      if (idx < (16 * AS2) / 2) a32[idx] = 0;
    }
  }
  __syncthreads();
  for (int idx = tid; idx < 800; idx += 256) {   // h from sG (f32) -> hi/lo
    int m = idx & 15, u = idx >> 4;
    float h = sG[u * 20 + m];
    unsigned short hb = f2bf(h);
    tA[m * AS2 + 6 + u]  = hb;
    tA[m * AS2 + 62 + u] = f2bf(h - bf2f(hb));
  }
  if (tid < 96) {
    int m = tid / 6, d = tid - (tid / 6) * 6;
    float f = state[(size_t)(r0 + m) * 832 + d];
    unsigned short h = f2bf(f);
    tA[m * AS2 + d]      = h;
    tA[m * AS2 + 56 + d] = f2bf(f - bf2f(h));
  }
  __syncthreads();

  // L1: K=112->128; w1 rows 0..5 self, 6..55 h; lo-halves reuse same hi weights
  mfma_layer<AS2>(tA, sG, wave, col, quad, 4, 10, 150,
    [&](int n) { return b1[n]; },
    [&](int k, int n) -> unsigned short {
      if (k < 56)  return hi_of(w1[k * 150 + n]);
      if (k < 112) return hi_of(w1[(k - 56) * 150 + n]);
      return (unsigned short)0;
    });
  __syncthreads();
  relu_fill_lo<AS2>(sG, tA, tid, 150, 150, 320);
  __syncthreads();

  // L2: K=300->320
  mfma_layer<AS2>(tA, sG, wave, col, quad, 10, 7, 100,
    [&](int n) { return b2[n]; },
    [&](int k, int n) -> unsigned short {
      if (k < 150) return hi_of(w2[k * 100 + n]);
      if (k < 300) return hi_of(w2[(k - 150) * 100 + n]);
      return (unsigned short)0;
    });
  __syncthreads();
  relu_fill_lo<AS2>(sG, tA, tid, 100, 100, 224);
  __syncthreads();

  // L3: K=200->224
  mfma_layer<AS2>(tA, sG, wave, col, quad, 7, 7, 100,
    [&](int n) { return b3[n]; },
    [&](int k, int n) -> unsigned short {
      if (k < 100) return hi_of(w3[k * 100 + n]);
      if (k < 200) return hi_of(w3[(k - 100) * 100 + n]);
      return (unsigned short)0;
    });
  __syncthreads();

  // L4: relu(sG) @ w4 + b4, f32, 16-lane shuffle reduce; f32 output
  {
    int m = tid >> 4, j0 = tid & 15;
    float s = 0.f;
    for (int j = j0; j < 100; j += 16)
      s += fmaxf(sG[j * 20 + m], 0.f) * w4[j];
    s += __shfl_xor(s, 8); s += __shfl_xor(s, 4);
    s += __shfl_xor(s, 2); s += __shfl_xor(s, 1);
    if (j0 == 0) out[r0 + m] = s + b4[0];
  }
}

extern "C" void kernel_launch(void* const* d_in, const int* in_sizes, int n_in,
                              void* d_out, int out_size, void* d_ws, size_t ws_size,
                              hipStream_t stream) {
  (void)in_sizes; (void)n_in; (void)d_ws; (void)ws_size; (void)out_size;
  // d_in[1..10] (mlp1_* / attn_*) are dead code in the reference — unused.
  // All buffers are float32 (R2 LDS-size forensics + R5 pass).
  const float* state = (const float*)d_in[0];
  const float* wih = (const float*)d_in[11];
  const float* whh = (const float*)d_in[12];
  const float* bih = (const float*)d_in[13];
  const float* bhh = (const float*)d_in[14];
  const float* w1  = (const float*)d_in[15];
  const float* b1  = (const float*)d_in[16];
  const float* w2  = (const float*)d_in[17];
  const float* b2  = (const float*)d_in[18];
  const float* w3  = (const float*)d_in[19];
  const float* b3  = (const float*)d_in[20];
  const float* w4  = (const float*)d_in[21];
  const float* b4  = (const float*)d_in[22];

  value_net_kernel<<<dim3(512), dim3(256), 0, stream>>>(
      state, wih, whh, bih, bhh, w1, b1, w2, b2, w3, b3, w4, b4,
      (float*)d_out);
}

// Round 7
// 336.509 us; speedup vs baseline: 1.3359x; 1.3359x over previous
//
#include <hip/hip_runtime.h>

typedef __attribute__((ext_vector_type(8))) short short8;
typedef __attribute__((ext_vector_type(4))) float f32x4;
union frag_u { short8 v; unsigned short u[8]; };

#define AS1 212   // LSTM ping-pong stride (106 dw; conflict-free for 16 cols)
#define AS2 328   // tail stride (164 dw -> 2-way, free per m136)

__device__ __forceinline__ float bf2f(unsigned short b) {
  unsigned int u = ((unsigned int)b) << 16;
  float f; __builtin_memcpy(&f, &u, 4); return f;
}
__device__ __forceinline__ unsigned short f2bf(float f) {
  unsigned int u; __builtin_memcpy(&u, &f, 4);
  return (unsigned short)((u + 0x7FFFu + ((u >> 16) & 1u)) >> 16);
}
__device__ __forceinline__ unsigned short hi_of(float f) { return f2bf(f); }
__device__ __forceinline__ unsigned short lo_of(float f) {
  unsigned short h = f2bf(f); return f2bf(f - bf2f(h));
}
__device__ __forceinline__ float sigm(float x) {
  return __builtin_amdgcn_rcpf(1.f + __expf(-x));
}
__device__ __forceinline__ float tanh_(float x) {
  return 1.f - 2.f * __builtin_amdgcn_rcpf(1.f + __expf(2.f * x));
}

// sA(16 x K bf16, stride AS) @ W(K x N) -> sG[n][m] (stride 20)
// A-frag: lane holds A[m=lane&15][k=kc*32+quad*8+j]; B-frag: W[k][n=tile*16+(lane&15)]
// C/D: row m = quad*4+reg, col n = lane&15   [bench-verified R2/R5/R6]
template <int AS, typename GetB, typename GetW>
__device__ __forceinline__ void mfma_layer(const unsigned short* sA, float* sG,
    int wave, int col, int quad, int kc_n, int ntiles, int N, GetB getb, GetW getw)
{
  for (int tile = wave; tile < ntiles; tile += 4) {
    int n = tile * 16 + col;
    float b = (n < N) ? getb(n) : 0.f;
    f32x4 acc = {b, b, b, b};
    for (int kc = 0; kc < kc_n; ++kc) {
      short8 a = *(const short8*)&sA[col * AS + kc * 32 + quad * 8];
      frag_u w;
      #pragma unroll
      for (int j = 0; j < 8; ++j) {
        int k = kc * 32 + quad * 8 + j;
        w.u[j] = (n < N) ? getw(k, n) : (unsigned short)0;
      }
      acc = __builtin_amdgcn_mfma_f32_16x16x32_bf16(a, w.v, acc, 0, 0, 0);
    }
    *(f32x4*)&sG[n * 20 + quad * 4] = acc;
  }
}

// relu(sG) -> sA: hi at [0,N), lo at [loOff,loOff+N), zero to Kpad  [bench-verified R5/R6]
template <int AS>
__device__ __forceinline__ void relu_fill_lo(const float* sG, unsigned short* sA,
                                             int tid, int N, int loOff, int Kpad) {
  for (int idx = tid; idx < 16 * Kpad; idx += 256) {
    int m = idx & 15, n = idx >> 4;
    unsigned short v = 0;
    if (n < N)                            v = f2bf(fmaxf(sG[n * 20 + m], 0.f));
    else if (n >= loOff && n < loOff + N) v = lo_of(fmaxf(sG[(n - loOff) * 20 + m], 0.f));
    sA[m * AS + n] = v;
  }
}

// __launch_bounds__(256, 2): R6 forensics — occupancy was register-limited
// (136 arch VGPR + ~96 AGPR wf > 256 combined -> 4 waves/CU, blocks serialized).
// Requesting 2 waves/EU caps combined at 256 -> 2 blocks/CU co-resident.
__global__ __launch_bounds__(256, 2) void value_net_kernel(
    const float* __restrict__ state,
    const float* __restrict__ wih, const float* __restrict__ whh,
    const float* __restrict__ bih, const float* __restrict__ bhh,
    const float* __restrict__ w1, const float* __restrict__ b1,
    const float* __restrict__ w2, const float* __restrict__ b2,
    const float* __restrict__ w3, const float* __restrict__ b3,
    const float* __restrict__ w4, const float* __restrict__ b4,
    float* __restrict__ out)
{
  // LSTM A cols (K=192): [x_hi 0..6 | x_lo 7..13 | x_hi 14..20 | h_hi 21..70 |
  //                       h_lo 71..120 | h_hi 121..170 | zero ..191]
  // paired W rows: [wih_hi | wih_hi | wih_lo | whh_hi | whh_hi | whh_lo]  (tri-product)
  __shared__ __align__(16) unsigned short sPP[2 * 16 * AS1];  // 13 568 B ping-pong
  __shared__ __align__(16) float sG[160 * 20];                // 12 800 B
  unsigned short* sA0 = sPP;
  unsigned short* sA1 = sPP + 16 * AS1;
  unsigned short* tA  = sPP;            // tail A (16*328 = 5248 ush <= 6784) aliases dead ping-pong

  const int tid  = threadIdx.x;
  const int wave = tid >> 6;
  const int lane = tid & 63;
  const int col  = lane & 15;
  const int quad = lane >> 4;
  const int r0   = blockIdx.x * 16;

  // ---- persistent gate-separated LSTM weight fragments (hi/lo from f32) ----
  const int  uu  = wave * 16 + col;
  const bool uok = uu < 50;
  frag_u wf[4][6];
  float  wb[4];
  #pragma unroll
  for (int g = 0; g < 4; ++g) {
    int c = g * 50 + uu;
    #pragma unroll
    for (int kc = 0; kc < 6; ++kc) {
      #pragma unroll
      for (int j = 0; j < 8; ++j) {
        int k = kc * 32 + quad * 8 + j;
        unsigned short w = 0;
        if (uok) {
          if (k < 7)        w = hi_of(wih[k * 200 + c]);
          else if (k < 14)  w = hi_of(wih[(k - 7) * 200 + c]);
          else if (k < 21)  w = lo_of(wih[(k - 14) * 200 + c]);
          else if (k < 71)  w = hi_of(whh[(k - 21) * 200 + c]);
          else if (k < 121) w = hi_of(whh[(k - 71) * 200 + c]);
          else if (k < 171) w = lo_of(whh[(k - 121) * 200 + c]);
        }
        wf[g][kc].u[j] = w;
      }
    }
    wb[g] = uok ? (bih[c] + bhh[c]) : 0.f;
  }

  // ---- x ownership: isx threads own (row xm, dim xd); prefetch x_0, x_1 ----
  const int  xm = tid / 7, xd = tid - (tid / 7) * 7;
  const bool isx = tid < 112;
  float xv0 = 0.f, xcur = 0.f;
  if (isx) {
    const float* xs = state + (size_t)(r0 + xm) * 832 + 6 + xd;
    xv0  = xs[0];
    xcur = xs[13];
  }

  // ---- zero both ping-pong buffers (h0 = 0 and all padding) ----
  {
    unsigned int* a32 = (unsigned int*)sPP;
    #pragma unroll
    for (int i = 0; i < 14; ++i) {
      int idx = tid + i * 256;
      if (idx < (2 * 16 * AS1) / 2) a32[idx] = 0;
    }
  }
  __syncthreads();
  if (isx) {   // x_0 into buf0
    unsigned short h = f2bf(xv0), l = f2bf(xv0 - bf2f(h));
    sA0[xm * AS1 + xd] = h; sA0[xm * AS1 + 7 + xd] = l; sA0[xm * AS1 + 14 + xd] = h;
  }
  __syncthreads();

  float cst[4] = {0.f, 0.f, 0.f, 0.f};

  // ---- LSTM: 64 steps, ONE barrier per step (ping-pong; write-set disjoint from read-set) ----
  for (int t = 0; t < 64; ++t) {
    const unsigned short* Ar = (t & 1) ? sA1 : sA0;
    unsigned short*       Aw = (t & 1) ? sA0 : sA1;

    // x_{t+2} load issued at top of body: whole step (~3k cyc) covers its latency,
    // so the end-of-step vmcnt wait is already satisfied.
    float xnext = 0.f;
    if (isx && t < 62)
      xnext = state[(size_t)(r0 + xm) * 832 + (t + 2) * 13 + 6 + xd];

    short8 a[6];
    #pragma unroll
    for (int kc = 0; kc < 6; ++kc)
      a[kc] = *(const short8*)&Ar[col * AS1 + kc * 32 + quad * 8];

    f32x4 G[4];
    #pragma unroll
    for (int g = 0; g < 4; ++g) {
      float b = wb[g];
      f32x4 acc = {b, b, b, b};
      #pragma unroll
      for (int kc = 0; kc < 6; ++kc)
        acc = __builtin_amdgcn_mfma_f32_16x16x32_bf16(a[kc], wf[g][kc].v, acc, 0, 0, 0);
      G[g] = acc;
    }

    // activation in registers: lane holds all 4 gates of unit uu, rows m = quad*4 + r
    #pragma unroll
    for (int r = 0; r < 4; ++r) {
      float si = sigm(G[0][r]);
      float sf = sigm(G[1][r]);
      float tg = tanh_(G[2][r]);
      float so = sigm(G[3][r]);
      float cc = sf * cst[r] + si * tg;
      cst[r] = cc;
      float h = so * tanh_(cc);
      if (uok) {
        int m = quad * 4 + r;
        if (t < 63) {
          unsigned short hb = f2bf(h);
          unsigned short hl = f2bf(h - bf2f(hb));
          Aw[m * AS1 + 21 + uu]  = hb;
          Aw[m * AS1 + 71 + uu]  = hl;
          Aw[m * AS1 + 121 + uu] = hb;
        } else {
          sG[uu * 20 + m] = h;     // final h, full f32, sG is dead during the loop
        }
      }
    }
    if (isx && t < 63) {   // x_{t+1} into Aw (cols 0..20, disjoint from h cols)
      unsigned short h = f2bf(xcur), l = f2bf(xcur - bf2f(h));
      Aw[xm * AS1 + xd] = h; Aw[xm * AS1 + 7 + xd] = l; Aw[xm * AS1 + 14 + xd] = h;
      xcur = xnext;
    }
    __syncthreads();
  }

  // ---- tail prep over the (dead) ping-pong region ----
  // joint cols (stride AS2): [self_hi 0..5 | h_hi 6..55 | self_lo 56..61 | h_lo 62..111 | 0 ..127]
  {
    unsigned int* a32 = (unsigned int*)tA;
    #pragma unroll
    for (int i = 0; i < 11; ++i) {
      int idx = tid + i * 256;
      if (idx < (16 * AS2) / 2) a32[idx] = 0;
    }
  }
  __syncthreads();
  for (int idx = tid; idx < 800; idx += 256) {   // h from sG (f32) -> hi/lo
    int m = idx & 15, u = idx >> 4;
    float h = sG[u * 20 + m];
    unsigned short hb = f2bf(h);
    tA[m * AS2 + 6 + u]  = hb;
    tA[m * AS2 + 62 + u] = f2bf(h - bf2f(hb));
  }
  if (tid < 96) {
    int m = tid / 6, d = tid - (tid / 6) * 6;
    float f = state[(size_t)(r0 + m) * 832 + d];
    unsigned short h = f2bf(f);
    tA[m * AS2 + d]      = h;
    tA[m * AS2 + 56 + d] = f2bf(f - bf2f(h));
  }
  __syncthreads();

  // L1: K=112->128; w1 rows 0..5 self, 6..55 h; lo-halves reuse same hi weights
  mfma_layer<AS2>(tA, sG, wave, col, quad, 4, 10, 150,
    [&](int n) { return b1[n]; },
    [&](int k, int n) -> unsigned short {
      if (k < 56)  return hi_of(w1[k * 150 + n]);
      if (k < 112) return hi_of(w1[(k - 56) * 150 + n]);
      return (unsigned short)0;
    });
  __syncthreads();
  relu_fill_lo<AS2>(sG, tA, tid, 150, 150, 320);
  __syncthreads();

  // L2: K=300->320
  mfma_layer<AS2>(tA, sG, wave, col, quad, 10, 7, 100,
    [&](int n) { return b2[n]; },
    [&](int k, int n) -> unsigned short {
      if (k < 150) return hi_of(w2[k * 100 + n]);
      if (k < 300) return hi_of(w2[(k - 150) * 100 + n]);
      return (unsigned short)0;
    });
  __syncthreads();
  relu_fill_lo<AS2>(sG, tA, tid, 100, 100, 224);
  __syncthreads();

  // L3: K=200->224
  mfma_layer<AS2>(tA, sG, wave, col, quad, 7, 7, 100,
    [&](int n) { return b3[n]; },
    [&](int k, int n) -> unsigned short {
      if (k < 100) return hi_of(w3[k * 100 + n]);
      if (k < 200) return hi_of(w3[(k - 100) * 100 + n]);
      return (unsigned short)0;
    });
  __syncthreads();

  // L4: relu(sG) @ w4 + b4, f32, 16-lane shuffle reduce; f32 output
  {
    int m = tid >> 4, j0 = tid & 15;
    float s = 0.f;
    for (int j = j0; j < 100; j += 16)
      s += fmaxf(sG[j * 20 + m], 0.f) * w4[j];
    s += __shfl_xor(s, 8); s += __shfl_xor(s, 4);
    s += __shfl_xor(s, 2); s += __shfl_xor(s, 1);
    if (j0 == 0) out[r0 + m] = s + b4[0];
  }
}

extern "C" void kernel_launch(void* const* d_in, const int* in_sizes, int n_in,
                              void* d_out, int out_size, void* d_ws, size_t ws_size,
                              hipStream_t stream) {
  (void)in_sizes; (void)n_in; (void)d_ws; (void)ws_size; (void)out_size;
  // d_in[1..10] (mlp1_* / attn_*) are dead code in the reference — unused.
  // All buffers are float32 (R2 LDS-size forensics + R5/R6 passes).
  const float* state = (const float*)d_in[0];
  const float* wih = (const float*)d_in[11];
  const float* whh = (const float*)d_in[12];
  const float* bih = (const float*)d_in[13];
  const float* bhh = (const float*)d_in[14];
  const float* w1  = (const float*)d_in[15];
  const float* b1  = (const float*)d_in[16];
  const float* w2  = (const float*)d_in[17];
  const float* b2  = (const float*)d_in[18];
  const float* w3  = (const float*)d_in[19];
  const float* b3  = (const float*)d_in[20];
  const float* w4  = (const float*)d_in[21];
  const float* b4  = (const float*)d_in[22];

  value_net_kernel<<<dim3(512), dim3(256), 0, stream>>>(
      state, wih, whh, bih, bhh, w1, b1, w2, b2, w3, b3, w4, b4,
      (float*)d_out);
}